// Round 11
// baseline (145.318 us; speedup 1.0000x reference)
//
#include <hip/hip_runtime.h>
#include <hip/hip_bf16.h>
#include <math.h>

#define Hd   1024
#define Bsz  4096
#define Kc   3072      // concatenated K (3 x 1024)
#define NT   48        // K-tiles of 64

typedef unsigned short u16;
typedef __attribute__((ext_vector_type(8))) u16 u16x8;
typedef __attribute__((ext_vector_type(2))) u16 u16x2;
typedef __attribute__((ext_vector_type(16))) float f32x16;
typedef __attribute__((ext_vector_type(8))) short bf16x8;

__device__ inline u16 f2bf(float f) {
    __hip_bfloat16 h = __float2bfloat16(f);
    return *reinterpret_cast<u16*>(&h);
}

__device__ inline float sigm(float x) { return 1.0f / (1.0f + __expf(-x)); }

__device__ inline void gload16(const void* g, const void* s) {
    __builtin_amdgcn_global_load_lds(
        (const __attribute__((address_space(1))) void*)g,
        (__attribute__((address_space(3))) void*)s, 16, 0, 0);
}

#define BAR()   __builtin_amdgcn_s_barrier()
#define VMW(n)  asm volatile("s_waitcnt vmcnt(" #n ")" ::: "memory")
#define PRIO1() __builtin_amdgcn_s_setprio(1)
#define PRIO0() __builtin_amdgcn_s_setprio(0)

// Blocked global layout for GEMM operands (A and B identical structure):
//   [blk32 = row/32][ktile = k/64][ks = (k%64)/16][hi = (k%16)/8][lane = row%32][8 u16]
// One (blk,ktile) chunk = 4*2*32*8 = 2048 u16 = 4 KB, contiguous.
// global_load_lds stages it linearly; ds_read_b128 fragment reads are the
// canonical contiguous-1KB-per-wave pattern => zero bank conflicts, no XOR.

// ---------------------------------------------------------------------------
// prep_A: A_cat bf16, interleaved rows m' = 4*r + gate, blocked layout.
// Block 0 additionally zeroes the z-row accumulator region of out.
// ---------------------------------------------------------------------------
__global__ __launch_bounds__(256) void prep_A(const float* __restrict__ U11,
                                              const float* __restrict__ U21,
                                              const float* __restrict__ W01,
                                              u16* __restrict__ Ab,
                                              float* __restrict__ out) {
    if (blockIdx.x == 0) {
        float* outz = out + (size_t)2 * Hd * Bsz;
        for (int i = threadIdx.x; i < Bsz; i += 256) outz[i] = 0.0f;
    }
    int t = blockIdx.x * 256 + threadIdx.x;
    int row = t / 384;
    int kc = (t - row * 384) * 8;
    int r = row >> 2, gate = row & 3;
    int sel = kc >> 10;
    int k = kc & 1023;
    const float* src = (sel == 0) ? W01 : ((sel == 1) ? U21 : U11);
    const float4* p = reinterpret_cast<const float4*>(src + (size_t)(gate * Hd + r) * Hd + k);
    float4 v0 = p[0], v1 = p[1];
    u16x8 o;
    o[0] = f2bf(v0.x); o[1] = f2bf(v0.y); o[2] = f2bf(v0.z); o[3] = f2bf(v0.w);
    o[4] = f2bf(v1.x); o[5] = f2bf(v1.y); o[6] = f2bf(v1.z); o[7] = f2bf(v1.w);
    int mb = row >> 5, r32 = row & 31;
    int kt = kc >> 6, ks = (kc >> 4) & 3, hi = (kc >> 3) & 1;
    size_t off = ((((size_t)mb * NT + kt) * 4 + ks) * 2 + hi) * 256 + r32 * 8;
    *reinterpret_cast<u16x8*>(Ab + off) = o;
}

// ---------------------------------------------------------------------------
// prep_B: B_cat bf16 (transpose + per-column z gating), blocked layout.
// Fused: z-row partial dot-products (w_row4096 . src) accumulated via atomicAdd.
// ---------------------------------------------------------------------------
__global__ __launch_bounds__(256) void prep_B(const float* __restrict__ hb,
                                              const float* __restrict__ ht,
                                              const float* __restrict__ hh,
                                              const float* __restrict__ z,
                                              const float* __restrict__ zb,
                                              const float* __restrict__ U11,
                                              const float* __restrict__ U21,
                                              const float* __restrict__ W01,
                                              u16* __restrict__ Bb,
                                              float* __restrict__ out) {
    __shared__ float tile[64][33];
    __shared__ float red[8][32];
    int n0 = blockIdx.x * 32;
    int kg0 = blockIdx.y * 64;
    int sel = kg0 >> 10;
    int k0 = kg0 & 1023;
    const float* src = (sel == 0) ? hb : ((sel == 1) ? ht : hh);
    const float* wsrc = (sel == 0) ? W01 : ((sel == 1) ? U21 : U11);
    int t = threadIdx.x, tx = t & 31, ty = t >> 5;
#pragma unroll
    for (int j = 0; j < 8; ++j) {
        int kk = ty * 8 + j;
        tile[kk][tx] = src[(size_t)(k0 + kk) * Bsz + n0 + tx];
    }
    __syncthreads();
    {   // bf16 transpose+gate write, blocked layout
        int kp = t & 31, ny = t >> 5;
        const int nb = n0 >> 5;                    // whole block shares nb
        const int kt = kg0 >> 6;
        const int kk2 = kp * 2;                    // k within tile: 0..62
        const int ks = kk2 >> 4, hi2 = (kk2 >> 3) & 1, e = kk2 & 7;
        const size_t base = ((((size_t)nb * NT + kt) * 4 + ks) * 2 + hi2) * 256 + e;
#pragma unroll
        for (int j = 0; j < 4; ++j) {
            int nl = ny * 4 + j;
            int n = n0 + nl;
            float s = (sel == 0) ? 1.0f : ((sel == 1) ? z[n] : zb[n]);
            u16x2 o;
            o[0] = f2bf(tile[kp * 2][nl] * s);
            o[1] = f2bf(tile[kp * 2 + 1][nl] * s);
            *reinterpret_cast<u16x2*>(Bb + base + nl * 8) = o;
        }
    }
    {   // fused z-row partial
        int col = t & 31, seg = t >> 5;
        const float* w = wsrc + (size_t)4096 * 1024 + k0 + seg * 8;
        float p = 0.0f;
#pragma unroll
        for (int j = 0; j < 8; ++j) p += w[j] * tile[seg * 8 + j][col];
        red[seg][col] = p;
        __syncthreads();
        if (seg == 0) {
            float tot = 0.0f;
#pragma unroll
            for (int q = 0; q < 8; ++q) tot += red[q][col];
            int n = n0 + col;
            float sca = (sel == 0) ? 1.0f : ((sel == 1) ? z[n] : zb[n]);
            atomicAdd(out + (size_t)2 * Hd * Bsz + n, tot * sca);
        }
    }
}

// ---------------------------------------------------------------------------
// gemm_fused: 256x256 tile, BK=64, 8 waves, 32x32x16 bf16 MFMA (R3's proven
// fragment/epilogue mapping), blocked conflict-free LDS layout (no XOR),
// R7's proven 4-phase counted-VMW(3) schedule:
//   entry invariant: outstanding <= {A1[T] 2nd issue, B1[T](2)} = 3
//   ph0: read A0,B0[T](12); stage A0[T+1]; VMW(3)->A1[T];   BAR; MFMA q00
//   ph1: read A1[T](8);     stage B0[T+1]; VMW(3)->B1[T];   BAR; MFMA q10
//   ph2: read B1[T](4);     stage A1[T+1];                  BAR; MFMA q11
//   ph3: (no reads)         stage B1[T+1]; VMW(3)->A0,B0';  BAR; MFMA q01
// Fused LSTM epilogue; bm==0 blocks finalize the z-row.
// ---------------------------------------------------------------------------
__global__ __launch_bounds__(512, 2) void gemm_fused(
    const u16* __restrict__ A, const u16* __restrict__ Bm,
    const float* __restrict__ c_in, const float* __restrict__ h_in,
    const float* __restrict__ z, const float* __restrict__ zb,
    const float* __restrict__ bias, float* __restrict__ out) {
    extern __shared__ __align__(16) u16 smem[];
    u16* const AsB = smem;            // [2buf][2half][8192 u16] = 64 KB
    u16* const BsB = smem + 32768;    // [2buf][2half][8192 u16] = 64 KB

    const int t = threadIdx.x;
    const int w = t >> 6, l = t & 63;
    const int wm = w >> 2, wn = w & 3;
    const int c = l & 31, hi = l >> 5;

    const int orig = blockIdx.x;                  // 256 wgs, bijective XCD swizzle
    const int wg = ((orig & 7) << 5) | (orig >> 3);
    const int bm = wg >> 4, bn = wg & 15;

    f32x16 acc[4][2];                             // [mh*2+mb][nh]
#pragma unroll
    for (int i = 0; i < 4; ++i)
#pragma unroll
        for (int j = 0; j < 2; ++j)
#pragma unroll
            for (int e = 0; e < 16; ++e) acc[i][j][e] = 0.0f;

    // staging: issue = 512 thr x 16B = 8 KB = 2 chunks, fully linear src+dst
    auto stageA = [&](int buf, int half, int kt) {
#pragma unroll
        for (int iss = 0; iss < 2; ++iss) {
            size_t mbg = (size_t)(bm * 8 + half * 4 + iss * 2 + (t >> 8));
            const u16* g = A + (mbg * NT + kt) * 2048 + (t & 255) * 8;
            const u16* d = AsB + buf * 16384 + half * 8192 + iss * 4096 + t * 8;
            gload16(g, d);
        }
    };
    auto stageB = [&](int buf, int half, int kt) {
#pragma unroll
        for (int iss = 0; iss < 2; ++iss) {
            size_t nbg = (size_t)(bn * 8 + half * 4 + iss * 2 + (t >> 8));
            const u16* g = Bm + (nbg * NT + kt) * 2048 + (t & 255) * 8;
            const u16* d = BsB + buf * 16384 + half * 8192 + iss * 4096 + t * 8;
            gload16(g, d);
        }
    };

    bf16x8 aF[2][2][4];   // [mh][mb][ks]
    bf16x8 bF[2][4];      // [nh][ks]

    auto readA = [&](int buf, int mh, int mb, int ks) -> bf16x8 {
        return *reinterpret_cast<const bf16x8*>(
            AsB + buf * 16384 + mh * 8192 + (wm * 2 + mb) * 2048 +
            (ks * 2 + hi) * 256 + c * 8);
    };
    auto readB = [&](int buf, int nh, int ks) -> bf16x8 {
        return *reinterpret_cast<const bf16x8*>(
            BsB + buf * 16384 + nh * 8192 + wn * 2048 +
            (ks * 2 + hi) * 256 + c * 8);
    };

#define MFMAQ(mh, nh)                                                         \
    PRIO1();                                                                  \
    _Pragma("unroll")                                                         \
    for (int mb = 0; mb < 2; ++mb)                                            \
        _Pragma("unroll")                                                     \
        for (int ks = 0; ks < 4; ++ks)                                        \
            acc[(mh)*2 + mb][nh] = __builtin_amdgcn_mfma_f32_32x32x16_bf16(   \
                aF[mh][mb][ks], bF[nh][ks], acc[(mh)*2 + mb][nh], 0, 0, 0);   \
    PRIO0()

    // prologue: stage tile 0 halves A0,B0,A1,B1; ensure A0,B0 complete
    stageA(0, 0, 0); stageB(0, 0, 0); stageA(0, 1, 0); stageB(0, 1, 0);
    VMW(3); BAR();

    for (int T = 0; T < NT; ++T) {
        const int p = T & 1, q2 = p ^ 1;
        const bool more = (T + 1 < NT);
        // ---- ph0: reads A0,B0[T]; stage A0[T+1]; guard A1[T]; MFMA q00
#pragma unroll
        for (int mb = 0; mb < 2; ++mb)
#pragma unroll
            for (int ks = 0; ks < 4; ++ks) aF[0][mb][ks] = readA(p, 0, mb, ks);
#pragma unroll
        for (int ks = 0; ks < 4; ++ks) bF[0][ks] = readB(p, 0, ks);
        if (more) { stageA(q2, 0, T + 1); VMW(3); } else { VMW(2); }
        BAR();
        MFMAQ(0, 0);
        // ---- ph1: reads A1[T]; stage B0[T+1]; guard B1[T]; MFMA q10
#pragma unroll
        for (int mb = 0; mb < 2; ++mb)
#pragma unroll
            for (int ks = 0; ks < 4; ++ks) aF[1][mb][ks] = readA(p, 1, mb, ks);
        if (more) { stageB(q2, 0, T + 1); VMW(3); } else { VMW(0); }
        BAR();
        MFMAQ(1, 0);
        // ---- ph2: reads B1[T]; stage A1[T+1]; MFMA q11
#pragma unroll
        for (int ks = 0; ks < 4; ++ks) bF[1][ks] = readB(p, 1, ks);
        if (more) stageA(q2, 1, T + 1);
        BAR();
        MFMAQ(1, 1);
        // ---- ph3: no reads; stage B1[T+1]; guard A0,B0[T+1]; MFMA q01
        if (more) { stageB(q2, 1, T + 1); VMW(3); }
        BAR();
        MFMAQ(0, 1);
    }

    // fused LSTM epilogue (R3-verified 32x32 C layout):
    // acc[mh*2+mb][nh] reg-quad q = f,i,o,g of unit u0+2q+hi, col n
    float zc[2], zbv[2];
#pragma unroll
    for (int nh = 0; nh < 2; ++nh) {
        int n = bn * 256 + nh * 128 + wn * 32 + c;
        zc[nh] = z[n]; zbv[nh] = zb[n];
    }
#pragma unroll
    for (int mh = 0; mh < 2; ++mh)
#pragma unroll
        for (int mb = 0; mb < 2; ++mb) {
            const int u0 = bm * 64 + mh * 32 + wm * 16 + mb * 8;
#pragma unroll
            for (int nh = 0; nh < 2; ++nh) {
                const int n = bn * 256 + nh * 128 + wn * 32 + c;
                const float zcv = zc[nh], zbvv = zbv[nh];
                const float nz = 1.0f - zcv, nzb = 1.0f - zbvv;
                f32x16 a = acc[mh * 2 + mb][nh];
#pragma unroll
                for (int q = 0; q < 4; ++q) {
                    const int r = u0 + 2 * q + hi;
                    const float co = c_in[(size_t)r * Bsz + n];
                    const float ho = h_in[(size_t)r * Bsz + n];
                    float fg = sigm(a[4 * q + 0] + bias[r]);
                    float ig = sigm(a[4 * q + 1] + bias[Hd + r]);
                    float og = sigm(a[4 * q + 2] + bias[2 * Hd + r]);
                    float gg = tanhf(a[4 * q + 3] + bias[3 * Hd + r]);
                    float i_g = ig * gg;
                    float cn = zcv * i_g + nz * nzb * co + nz * zbvv * (fg * co + i_g);
                    float tc2 = tanhf(cn);
                    float hn = zcv * og * tc2 + nz * nzb * ho + nz * zbvv * og * tc2;
                    out[(size_t)r * Bsz + n] = hn;
                    out[(size_t)Hd * Bsz + (size_t)r * Bsz + n] = cn;
                }
            }
        }

    // z-row finalize (16 blocks with bm==0 cover all 4096 columns)
    if (bm == 0 && t < 256) {
        float* outz = out + (size_t)2 * Hd * Bsz;
        int n = bn * 256 + t;
        float s = outz[n] + bias[4096];
        float zh = (s + 1.0f) * 0.5f;
        zh = fminf(fmaxf(zh, 0.0f), 1.0f);
        outz[n] = (zh > 0.5f) ? 1.0f : 0.0f;
    }
#undef MFMAQ
}

extern "C" void kernel_launch(void* const* d_in, const int* in_sizes, int n_in,
                              void* d_out, int out_size, void* d_ws, size_t ws_size,
                              hipStream_t stream) {
    (void)in_sizes; (void)n_in; (void)out_size; (void)ws_size;
    const float* c    = (const float*)d_in[0];
    const float* hb   = (const float*)d_in[1];
    const float* h    = (const float*)d_in[2];
    const float* ht   = (const float*)d_in[3];
    const float* z    = (const float*)d_in[4];
    const float* zb   = (const float*)d_in[5];
    const float* U11  = (const float*)d_in[6];
    const float* U21  = (const float*)d_in[7];
    const float* W01  = (const float*)d_in[8];
    const float* bias = (const float*)d_in[9];
    float* out = (float*)d_out;

    u16* Ab = (u16*)d_ws;                          // 25.2 MB
    u16* Bb = Ab + (size_t)4096 * Kc;              // 25.2 MB

    hipFuncSetAttribute(reinterpret_cast<const void*>(gemm_fused),
                        hipFuncAttributeMaxDynamicSharedMemorySize, 131072);

    prep_A<<<6144, 256, 0, stream>>>(U11, U21, W01, Ab, out);
    prep_B<<<dim3(128, 48), 256, 0, stream>>>(hb, ht, h, z, zb, U11, U21, W01, Bb, out);
    gemm_fused<<<256, 512, 131072, stream>>>(Ab, Bb, c, h, z, zb, bias, out);
}

// Round 12
// 123.347 us; speedup vs baseline: 1.1781x; 1.1781x over previous
//
#include <hip/hip_runtime.h>
#include <hip/hip_bf16.h>
#include <math.h>

#define Hd   1024
#define Bsz  4096
#define Kc   3072      // concatenated K (3 x 1024)
#define NTt  96        // K-tiles of 32
#define CH   512       // u16 per chunk: 16 rows x 32 k

typedef unsigned short u16;
typedef __attribute__((ext_vector_type(8))) u16 u16x8;
typedef __attribute__((ext_vector_type(4))) float f32x4;
typedef __attribute__((ext_vector_type(8))) short bf16x8;

__device__ inline u16 f2bf(float f) {
    __hip_bfloat16 h = __float2bfloat16(f);
    return *reinterpret_cast<u16*>(&h);
}

__device__ inline float sigm(float x) { return 1.0f / (1.0f + __expf(-x)); }

__device__ inline void gload16(const void* g, const void* s) {
    __builtin_amdgcn_global_load_lds(
        (const __attribute__((address_space(1))) void*)g,
        (__attribute__((address_space(3))) void*)s, 16, 0, 0);
}

#define BAR()   __builtin_amdgcn_s_barrier()
#define VMW(n)  asm volatile("s_waitcnt vmcnt(" #n ")" ::: "memory")
#define PRIO1() __builtin_amdgcn_s_setprio(1)
#define PRIO0() __builtin_amdgcn_s_setprio(0)

// Blocked operand layout (A and B identical): chunk = (rowblk16, ktile32):
//   global[(rowblk*96 + kt)*512 + (g*16 + row%16)*8 + e],  g=(k%32)/8, e=k%8
// GEMM frag read = chunkbase + lane*16B  -> canonical zero-conflict pattern
// (verified 0 conflicts in R11). Staging via global_load_lds is linear.

// ---------------------------------------------------------------------------
// prep_A: A_cat bf16 blocked; row m' = 4*r + gate <- src row gate*1024+r.
// LDS-staged so global writes are contiguous 1KB chunks.
// Block (mb, kb): 16 rows x 512 k = 16 chunks. Block (0,0) zeroes z-row acc.
// ---------------------------------------------------------------------------
__global__ __launch_bounds__(256) void prep_A(const float* __restrict__ U11,
                                              const float* __restrict__ U21,
                                              const float* __restrict__ W01,
                                              u16* __restrict__ Ab,
                                              float* __restrict__ out) {
    __shared__ u16 lds[16 * 520];                 // 520 = 512 + 8 pad (16B)
    if (blockIdx.x == 0 && blockIdx.y == 0) {
        float* outz = out + (size_t)2 * Hd * Bsz;
        for (int i = threadIdx.x; i < Bsz; i += 256) outz[i] = 0.0f;
    }
    const int mb = blockIdx.x, kb = blockIdx.y;   // mb<256, kb<6
    const int t = threadIdx.x;
    const int r16 = t >> 4, j = t & 15;           // row-in-block, ktile-in-slab
    const int row = mb * 16 + r16, gate = row & 3, r = row >> 2;
    const int sel = kb >> 1;
    const int k0 = (kb & 1) * 512 + j * 32;
    const float* src = (sel == 0) ? W01 : ((sel == 1) ? U21 : U11);
    const float4* p = reinterpret_cast<const float4*>(
        src + ((size_t)(gate * Hd + r)) * Hd + k0);
#pragma unroll
    for (int g = 0; g < 4; ++g) {
        float4 v0 = p[g * 2], v1 = p[g * 2 + 1];
        u16x8 o;
        o[0] = f2bf(v0.x); o[1] = f2bf(v0.y); o[2] = f2bf(v0.z); o[3] = f2bf(v0.w);
        o[4] = f2bf(v1.x); o[5] = f2bf(v1.y); o[6] = f2bf(v1.z); o[7] = f2bf(v1.w);
        *reinterpret_cast<u16x8*>(&lds[j * 520 + (g * 16 + r16) * 8]) = o;
    }
    __syncthreads();
    const int c = t >> 4, jj = t & 15;            // chunk, lane-in-chunk
    u16* gdst = Ab + ((size_t)(mb * NTt + kb * 16 + c)) * CH;
#pragma unroll
    for (int i = 0; i < 4; ++i)
        *reinterpret_cast<u16x8*>(gdst + i * 128 + jj * 8) =
            *reinterpret_cast<const u16x8*>(&lds[c * 520 + i * 128 + jj * 8]);
}

// ---------------------------------------------------------------------------
// prep_B: B_cat bf16 blocked (transpose + per-column z gating), LDS-staged,
// contiguous 1KB chunk writes. Fused z-row partials via atomicAdd.
// Block (n0=bx*32, kg0=by*64) -> 4 chunks.
// ---------------------------------------------------------------------------
__global__ __launch_bounds__(256) void prep_B(const float* __restrict__ hb,
                                              const float* __restrict__ ht,
                                              const float* __restrict__ hh,
                                              const float* __restrict__ z,
                                              const float* __restrict__ zb,
                                              const float* __restrict__ U11,
                                              const float* __restrict__ U21,
                                              const float* __restrict__ W01,
                                              u16* __restrict__ Bb,
                                              float* __restrict__ out) {
    __shared__ float tile[64][33];
    __shared__ float red[8][32];
    const int n0 = blockIdx.x * 32;
    const int kg0 = blockIdx.y * 64;
    const int sel = kg0 >> 10;
    const int k0 = kg0 & 1023;
    const float* src = (sel == 0) ? hb : ((sel == 1) ? ht : hh);
    const float* wsrc = (sel == 0) ? W01 : ((sel == 1) ? U21 : U11);
    const int t = threadIdx.x, tx = t & 31, ty = t >> 5;
#pragma unroll
    for (int j = 0; j < 8; ++j) {
        int kk = ty * 8 + j;
        tile[kk][tx] = src[(size_t)(k0 + kk) * Bsz + n0 + tx];
    }
    __syncthreads();
    {   // blocked bf16 write-out: wave w handles chunk c=w
        const int c = t >> 6, l = t & 63, g = l >> 4, n16 = l & 15;
        const int kt_loc = c & 1, nb_loc = c >> 1;
        const int nl = nb_loc * 16 + n16;
        const int n = n0 + nl;
        const float s = (sel == 0) ? 1.0f : ((sel == 1) ? z[n] : zb[n]);
        u16x8 o;
#pragma unroll
        for (int e = 0; e < 8; ++e)
            o[e] = f2bf(tile[kt_loc * 32 + g * 8 + e][nl] * s);
        const int nb = (n0 >> 4) + nb_loc, kt = (kg0 >> 5) + kt_loc;
        *reinterpret_cast<u16x8*>(Bb + ((size_t)(nb * NTt + kt)) * CH +
                                  (g * 16 + n16) * 8) = o;
    }
    {   // fused z-row partial
        int col = t & 31, seg = t >> 5;
        const float* w = wsrc + (size_t)4096 * 1024 + k0 + seg * 8;
        float p = 0.0f;
#pragma unroll
        for (int j = 0; j < 8; ++j) p += w[j] * tile[seg * 8 + j][col];
        red[seg][col] = p;
        __syncthreads();
        if (seg == 0) {
            float tot = 0.0f;
#pragma unroll
            for (int q = 0; q < 8; ++q) tot += red[q][col];
            int n = n0 + col;
            float sca = (sel == 0) ? 1.0f : ((sel == 1) ? z[n] : zb[n]);
            atomicAdd(out + (size_t)2 * Hd * Bsz + n, tot * sca);
        }
    }
}

// ---------------------------------------------------------------------------
// gemm_fused: BM=256 x BN=128, BK=32, grid 512 -> 2 blocks/CU (48 KB LDS,
// <=128 VGPR via __launch_bounds__(512,4)), 8 waves (2M x 4N), per-wave
// 128x32 output, 16 fully-independent 16x16x32 MFMA per K-tile.
// Per K-tile: stage 3 issues (A=2, B=1) -> VMW(3) (guards prev tile's 3,
// 1 full tile in flight) -> BAR -> 10 chunk-linear ds_reads (0 conflicts)
// -> 16 MFMA -> BAR (WAR). TLP across the 2 resident blocks hides stalls.
// Fused LSTM epilogue; bm==0 blocks finalize the z-row.
// ---------------------------------------------------------------------------
__global__ __launch_bounds__(512, 4) void gemm_fused(
    const u16* __restrict__ A, const u16* __restrict__ Bm,
    const float* __restrict__ c_in, const float* __restrict__ h_in,
    const float* __restrict__ z, const float* __restrict__ zb,
    const float* __restrict__ bias, float* __restrict__ out) {
    extern __shared__ __align__(16) u16 smem[];
    u16* const As = smem;             // [2][8192 u16] = 32 KB
    u16* const Bs = smem + 16384;     // [2][4096 u16] = 16 KB

    const int t = threadIdx.x;
    const int w = t >> 6, l = t & 63;
    const int wm = w >> 2, wn = w & 3;
    const int fr = l & 15, fq = l >> 4;

    const int orig = blockIdx.x;                  // 512 wgs, bijective XCD swizzle
    const int wg = ((orig & 7) << 6) | (orig >> 3);
    const int bm = wg >> 5, bn = wg & 31;         // 16 x 32 tiles

    f32x4 acc[8][2];
#pragma unroll
    for (int i = 0; i < 8; ++i)
#pragma unroll
        for (int j = 0; j < 2; ++j) acc[i][j] = (f32x4){0.f, 0.f, 0.f, 0.f};

    auto stageA = [&](int buf, int kt) {          // 2 issues: 16 chunks
#pragma unroll
        for (int iss = 0; iss < 2; ++iss) {
            int mb = bm * 16 + iss * 8 + w;       // wave loads one chunk/issue
            gload16(A + ((size_t)(mb * NTt + kt)) * CH + l * 8,
                    As + buf * 8192 + iss * 4096 + w * 512 + l * 8);
        }
    };
    auto stageB = [&](int buf, int kt) {          // 1 issue: 8 chunks
        int nb = bn * 8 + w;
        gload16(Bm + ((size_t)(nb * NTt + kt)) * CH + l * 8,
                Bs + buf * 4096 + w * 512 + l * 8);
    };

    // prologue: stage tile 0 (3 issues outstanding into loop)
    stageA(0, 0); stageB(0, 0);

    for (int T = 0; T < NTt; ++T) {
        const int p = T & 1;
        if (T + 1 < NTt) {
            stageA(p ^ 1, T + 1); stageB(p ^ 1, T + 1);
            VMW(3);                               // tile T's 3 loads complete
        } else {
            VMW(0);
        }
        BAR();                                    // publish LDS across waves
        const u16* Ap = As + p * 8192;
        const u16* Bpp = Bs + p * 4096;
        bf16x8 bF0 = *reinterpret_cast<const bf16x8*>(Bpp + (wn * 2 + 0) * CH + l * 8);
        bf16x8 bF1 = *reinterpret_cast<const bf16x8*>(Bpp + (wn * 2 + 1) * CH + l * 8);
        PRIO1();
#pragma unroll
        for (int h2 = 0; h2 < 2; ++h2) {
            bf16x8 a0 = *reinterpret_cast<const bf16x8*>(Ap + (wm * 8 + h2 * 4 + 0) * CH + l * 8);
            bf16x8 a1 = *reinterpret_cast<const bf16x8*>(Ap + (wm * 8 + h2 * 4 + 1) * CH + l * 8);
            bf16x8 a2 = *reinterpret_cast<const bf16x8*>(Ap + (wm * 8 + h2 * 4 + 2) * CH + l * 8);
            bf16x8 a3 = *reinterpret_cast<const bf16x8*>(Ap + (wm * 8 + h2 * 4 + 3) * CH + l * 8);
            acc[h2 * 4 + 0][0] = __builtin_amdgcn_mfma_f32_16x16x32_bf16(a0, bF0, acc[h2 * 4 + 0][0], 0, 0, 0);
            acc[h2 * 4 + 0][1] = __builtin_amdgcn_mfma_f32_16x16x32_bf16(a0, bF1, acc[h2 * 4 + 0][1], 0, 0, 0);
            acc[h2 * 4 + 1][0] = __builtin_amdgcn_mfma_f32_16x16x32_bf16(a1, bF0, acc[h2 * 4 + 1][0], 0, 0, 0);
            acc[h2 * 4 + 1][1] = __builtin_amdgcn_mfma_f32_16x16x32_bf16(a1, bF1, acc[h2 * 4 + 1][1], 0, 0, 0);
            acc[h2 * 4 + 2][0] = __builtin_amdgcn_mfma_f32_16x16x32_bf16(a2, bF0, acc[h2 * 4 + 2][0], 0, 0, 0);
            acc[h2 * 4 + 2][1] = __builtin_amdgcn_mfma_f32_16x16x32_bf16(a2, bF1, acc[h2 * 4 + 2][1], 0, 0, 0);
            acc[h2 * 4 + 3][0] = __builtin_amdgcn_mfma_f32_16x16x32_bf16(a3, bF0, acc[h2 * 4 + 3][0], 0, 0, 0);
            acc[h2 * 4 + 3][1] = __builtin_amdgcn_mfma_f32_16x16x32_bf16(a3, bF1, acc[h2 * 4 + 3][1], 0, 0, 0);
        }
        PRIO0();
        BAR();                                    // WAR: reads done before next stage
    }

    // fused LSTM epilogue: acc[mi][ni] regs = f,i,o,g of unit r, col n
    float zc[2], zbv[2];
#pragma unroll
    for (int ni = 0; ni < 2; ++ni) {
        int n = bn * 128 + wn * 32 + ni * 16 + fr;
        zc[ni] = z[n]; zbv[ni] = zb[n];
    }
#pragma unroll
    for (int mi = 0; mi < 8; ++mi) {
        const int r = bm * 64 + wm * 32 + mi * 4 + fq;
        const float b0 = bias[r], b1 = bias[Hd + r];
        const float b2 = bias[2 * Hd + r], b3 = bias[3 * Hd + r];
        const float* crow = c_in + (size_t)r * Bsz;
        const float* hrow = h_in + (size_t)r * Bsz;
        float* hout = out + (size_t)r * Bsz;
        float* cout = out + (size_t)Hd * Bsz + (size_t)r * Bsz;
#pragma unroll
        for (int ni = 0; ni < 2; ++ni) {
            const int n = bn * 128 + wn * 32 + ni * 16 + fr;
            f32x4 a = acc[mi][ni];
            float co = crow[n], ho = hrow[n];
            float fg = sigm(a[0] + b0);
            float ig = sigm(a[1] + b1);
            float og = sigm(a[2] + b2);
            float gg = tanhf(a[3] + b3);
            float i_g = ig * gg;
            float nz = 1.0f - zc[ni], nzb = 1.0f - zbv[ni];
            float cn = zc[ni] * i_g + nz * nzb * co + nz * zbv[ni] * (fg * co + i_g);
            float tc2 = tanhf(cn);
            float hn = zc[ni] * og * tc2 + nz * nzb * ho + nz * zbv[ni] * og * tc2;
            hout[n] = hn; cout[n] = cn;
        }
    }

    // z-row finalize (32 blocks with bm==0 cover all 4096 columns)
    if (bm == 0 && t < 128) {
        float* outz = out + (size_t)2 * Hd * Bsz;
        int n = bn * 128 + t;
        float s = outz[n] + bias[4096];
        float zh = (s + 1.0f) * 0.5f;
        zh = fminf(fmaxf(zh, 0.0f), 1.0f);
        outz[n] = (zh > 0.5f) ? 1.0f : 0.0f;
    }
}

extern "C" void kernel_launch(void* const* d_in, const int* in_sizes, int n_in,
                              void* d_out, int out_size, void* d_ws, size_t ws_size,
                              hipStream_t stream) {
    (void)in_sizes; (void)n_in; (void)out_size; (void)ws_size;
    const float* c    = (const float*)d_in[0];
    const float* hb   = (const float*)d_in[1];
    const float* h    = (const float*)d_in[2];
    const float* ht   = (const float*)d_in[3];
    const float* z    = (const float*)d_in[4];
    const float* zb   = (const float*)d_in[5];
    const float* U11  = (const float*)d_in[6];
    const float* U21  = (const float*)d_in[7];
    const float* W01  = (const float*)d_in[8];
    const float* bias = (const float*)d_in[9];
    float* out = (float*)d_out;

    u16* Ab = (u16*)d_ws;                          // 256*96*512*2B = 25.2 MB
    u16* Bb = Ab + (size_t)256 * NTt * CH;         // 25.2 MB

    hipFuncSetAttribute(reinterpret_cast<const void*>(gemm_fused),
                        hipFuncAttributeMaxDynamicSharedMemorySize, 49152);

    prep_A<<<dim3(256, 6), 256, 0, stream>>>(U11, U21, W01, Ab, out);
    prep_B<<<dim3(128, 48), 256, 0, stream>>>(hb, ht, h, z, zb, U11, U21, W01, Bb, out);
    gemm_fused<<<512, 512, 49152, stream>>>(Ab, Bb, c, h, z, zb, bias, out);
}

// Round 13
// 120.254 us; speedup vs baseline: 1.2084x; 1.0257x over previous
//
#include <hip/hip_runtime.h>
#include <hip/hip_bf16.h>
#include <math.h>

#define Hd   1024
#define Bsz  4096
#define Kc   3072      // concatenated K (3 x 1024)
#define NTt  96        // K-tiles of 32
#define CH   512       // u16 per chunk: 16 rows x 32 k

typedef unsigned short u16;
typedef __attribute__((ext_vector_type(8))) u16 u16x8;
typedef __attribute__((ext_vector_type(4))) float f32x4;
typedef __attribute__((ext_vector_type(8))) short bf16x8;

__device__ inline u16 f2bf(float f) {
    __hip_bfloat16 h = __float2bfloat16(f);
    return *reinterpret_cast<u16*>(&h);
}

__device__ inline float sigm(float x) { return 1.0f / (1.0f + __expf(-x)); }

__device__ inline void gload16(const void* g, const void* s) {
    __builtin_amdgcn_global_load_lds(
        (const __attribute__((address_space(1))) void*)g,
        (__attribute__((address_space(3))) void*)s, 16, 0, 0);
}

#define BAR()   __builtin_amdgcn_s_barrier()
#define VMW(n)  asm volatile("s_waitcnt vmcnt(" #n ")" ::: "memory")
#define PRIO1() __builtin_amdgcn_s_setprio(1)
#define PRIO0() __builtin_amdgcn_s_setprio(0)

// Blocked operand layout (A and B identical): chunk = (rowblk16, ktile32):
//   global[(rowblk*96 + kt)*512 + (g*16 + row%16)*8 + e],  g=(k%32)/8, e=k%8
// Fragment read = chunkbase + lane*16B -> canonical zero-conflict pattern
// (verified 0 conflicts R11/R12); matches 16x16x32 A/B operand lane mapping.

// ---------------------------------------------------------------------------
// prep_A: A_cat bf16 blocked; row m' = 4*r + gate <- src row gate*1024+r.
// LDS-staged so global writes are contiguous 1KB chunks. (R12-verified)
// ---------------------------------------------------------------------------
__global__ __launch_bounds__(256) void prep_A(const float* __restrict__ U11,
                                              const float* __restrict__ U21,
                                              const float* __restrict__ W01,
                                              u16* __restrict__ Ab,
                                              float* __restrict__ out) {
    __shared__ u16 lds[16 * 520];
    if (blockIdx.x == 0 && blockIdx.y == 0) {
        float* outz = out + (size_t)2 * Hd * Bsz;
        for (int i = threadIdx.x; i < Bsz; i += 256) outz[i] = 0.0f;
    }
    const int mb = blockIdx.x, kb = blockIdx.y;   // mb<256, kb<6
    const int t = threadIdx.x;
    const int r16 = t >> 4, j = t & 15;
    const int row = mb * 16 + r16, gate = row & 3, r = row >> 2;
    const int sel = kb >> 1;
    const int k0 = (kb & 1) * 512 + j * 32;
    const float* src = (sel == 0) ? W01 : ((sel == 1) ? U21 : U11);
    const float4* p = reinterpret_cast<const float4*>(
        src + ((size_t)(gate * Hd + r)) * Hd + k0);
#pragma unroll
    for (int g = 0; g < 4; ++g) {
        float4 v0 = p[g * 2], v1 = p[g * 2 + 1];
        u16x8 o;
        o[0] = f2bf(v0.x); o[1] = f2bf(v0.y); o[2] = f2bf(v0.z); o[3] = f2bf(v0.w);
        o[4] = f2bf(v1.x); o[5] = f2bf(v1.y); o[6] = f2bf(v1.z); o[7] = f2bf(v1.w);
        *reinterpret_cast<u16x8*>(&lds[j * 520 + (g * 16 + r16) * 8]) = o;
    }
    __syncthreads();
    const int c = t >> 4, jj = t & 15;
    u16* gdst = Ab + ((size_t)(mb * NTt + kb * 16 + c)) * CH;
#pragma unroll
    for (int i = 0; i < 4; ++i)
        *reinterpret_cast<u16x8*>(gdst + i * 128 + jj * 8) =
            *reinterpret_cast<const u16x8*>(&lds[c * 520 + i * 128 + jj * 8]);
}

// ---------------------------------------------------------------------------
// prep_B: B_cat bf16 blocked (transpose + per-column z gating), contiguous
// chunk writes. Fused z-row partials via atomicAdd. (R12-verified)
// ---------------------------------------------------------------------------
__global__ __launch_bounds__(256) void prep_B(const float* __restrict__ hb,
                                              const float* __restrict__ ht,
                                              const float* __restrict__ hh,
                                              const float* __restrict__ z,
                                              const float* __restrict__ zb,
                                              const float* __restrict__ U11,
                                              const float* __restrict__ U21,
                                              const float* __restrict__ W01,
                                              u16* __restrict__ Bb,
                                              float* __restrict__ out) {
    __shared__ float tile[64][33];
    __shared__ float red[8][32];
    const int n0 = blockIdx.x * 32;
    const int kg0 = blockIdx.y * 64;
    const int sel = kg0 >> 10;
    const int k0 = kg0 & 1023;
    const float* src = (sel == 0) ? hb : ((sel == 1) ? ht : hh);
    const float* wsrc = (sel == 0) ? W01 : ((sel == 1) ? U21 : U11);
    const int t = threadIdx.x, tx = t & 31, ty = t >> 5;
#pragma unroll
    for (int j = 0; j < 8; ++j) {
        int kk = ty * 8 + j;
        tile[kk][tx] = src[(size_t)(k0 + kk) * Bsz + n0 + tx];
    }
    __syncthreads();
    {   // blocked bf16 write-out: wave w handles chunk c=w
        const int c = t >> 6, l = t & 63, g = l >> 4, n16 = l & 15;
        const int kt_loc = c & 1, nb_loc = c >> 1;
        const int nl = nb_loc * 16 + n16;
        const int n = n0 + nl;
        const float s = (sel == 0) ? 1.0f : ((sel == 1) ? z[n] : zb[n]);
        u16x8 o;
#pragma unroll
        for (int e = 0; e < 8; ++e)
            o[e] = f2bf(tile[kt_loc * 32 + g * 8 + e][nl] * s);
        const int nb = (n0 >> 4) + nb_loc, kt = (kg0 >> 5) + kt_loc;
        *reinterpret_cast<u16x8*>(Bb + ((size_t)(nb * NTt + kt)) * CH +
                                  (g * 16 + n16) * 8) = o;
    }
    {   // fused z-row partial
        int col = t & 31, seg = t >> 5;
        const float* w = wsrc + (size_t)4096 * 1024 + k0 + seg * 8;
        float p = 0.0f;
#pragma unroll
        for (int j = 0; j < 8; ++j) p += w[j] * tile[seg * 8 + j][col];
        red[seg][col] = p;
        __syncthreads();
        if (seg == 0) {
            float tot = 0.0f;
#pragma unroll
            for (int q = 0; q < 8; ++q) tot += red[q][col];
            int n = n0 + col;
            float sca = (sel == 0) ? 1.0f : ((sel == 1) ? z[n] : zb[n]);
            atomicAdd(out + (size_t)2 * Hd * Bsz + n, tot * sca);
        }
    }
}

// ---------------------------------------------------------------------------
// gemm_fused: BM=256 x BN=128, BK=32, 256 thr / 4 waves (2M x 2N), per-wave
// output 128x64 (R7's LDS economy: 12 b128 reads -> 32 independent MFMA,
// 23 B/KFLOP), grid 512 -> 2 blocks/CU (48 KB LDS, 2 barrier domains ->
// R12's TLP hides sync). Per K-tile: stage T+1 (6 issues) -> VMW(6) guards
// tile-T loads (1 full tile old) -> BAR -> 12 chunk-linear ds_reads (0
// conflicts) -> 32-MFMA burst -> BAR. Fused LSTM epilogue; bm==0 blocks
// finalize the z-row.
// ---------------------------------------------------------------------------
__global__ __launch_bounds__(256, 2) void gemm_fused(
    const u16* __restrict__ A, const u16* __restrict__ Bm,
    const float* __restrict__ c_in, const float* __restrict__ h_in,
    const float* __restrict__ z, const float* __restrict__ zb,
    const float* __restrict__ bias, float* __restrict__ out) {
    extern __shared__ __align__(16) u16 smem[];
    u16* const As = smem;             // [2][8192 u16] = 32 KB
    u16* const Bs = smem + 16384;     // [2][4096 u16] = 16 KB

    const int t = threadIdx.x;
    const int w = t >> 6, l = t & 63;
    const int wm = w >> 1, wn = w & 1;
    const int fr = l & 15, fq = l >> 4;

    const int orig = blockIdx.x;                  // 512 wgs, bijective XCD swizzle
    const int wg = ((orig & 7) << 6) | (orig >> 3);
    const int bm = wg >> 5, bn = wg & 31;         // 16 x 32 tiles

    f32x4 acc[8][4];
#pragma unroll
    for (int i = 0; i < 8; ++i)
#pragma unroll
        for (int j = 0; j < 4; ++j) acc[i][j] = (f32x4){0.f, 0.f, 0.f, 0.f};

    const int tc = t >> 6, te = t & 63;           // issue sub-chunk, lane
    auto stageA = [&](int buf, int kt) {          // 4 issues: 16 chunks (16 KB)
#pragma unroll
        for (int i = 0; i < 4; ++i)
            gload16(A + ((size_t)((bm * 16 + i * 4 + tc) * NTt + kt)) * CH + te * 8,
                    As + buf * 8192 + i * 2048 + t * 8);
    };
    auto stageB = [&](int buf, int kt) {          // 2 issues: 8 chunks (8 KB)
#pragma unroll
        for (int i = 0; i < 2; ++i)
            gload16(Bm + ((size_t)((bn * 8 + i * 4 + tc) * NTt + kt)) * CH + te * 8,
                    Bs + buf * 4096 + i * 2048 + t * 8);
    };

    // prologue: stage tile 0 (6 issues in flight)
    stageA(0, 0); stageB(0, 0);

    for (int T = 0; T < NTt; ++T) {
        const int p = T & 1;
        if (T + 1 < NTt) {
            stageA(p ^ 1, T + 1); stageB(p ^ 1, T + 1);
            VMW(6);                               // tile T's 6 loads complete
        } else {
            VMW(0);
        }
        BAR();
        const u16* Ap = As + p * 8192;
        const u16* Bp = Bs + p * 4096;
        bf16x8 aF[8], bF[4];
#pragma unroll
        for (int mi = 0; mi < 8; ++mi)
            aF[mi] = *reinterpret_cast<const bf16x8*>(Ap + (wm * 8 + mi) * CH + l * 8);
#pragma unroll
        for (int ni = 0; ni < 4; ++ni)
            bF[ni] = *reinterpret_cast<const bf16x8*>(Bp + (wn * 4 + ni) * CH + l * 8);
        PRIO1();
#pragma unroll
        for (int mi = 0; mi < 8; ++mi)
#pragma unroll
            for (int ni = 0; ni < 4; ++ni)
                acc[mi][ni] = __builtin_amdgcn_mfma_f32_16x16x32_bf16(
                    aF[mi], bF[ni], acc[mi][ni], 0, 0, 0);
        PRIO0();
        BAR();                                    // WAR before next stage
    }

    // fused LSTM epilogue: acc[mi][ni] regs = f,i,o,g of unit u, col n
    float zc[4], zbv[4];
#pragma unroll
    for (int ni = 0; ni < 4; ++ni) {
        int n = bn * 128 + wn * 64 + ni * 16 + fr;
        zc[ni] = z[n]; zbv[ni] = zb[n];
    }
#pragma unroll
    for (int mi = 0; mi < 8; ++mi) {
        const int u = bm * 64 + wm * 32 + mi * 4 + fq;
        const float b0 = bias[u], b1 = bias[Hd + u];
        const float b2 = bias[2 * Hd + u], b3 = bias[3 * Hd + u];
        const float* crow = c_in + (size_t)u * Bsz;
        const float* hrow = h_in + (size_t)u * Bsz;
        float* hout = out + (size_t)u * Bsz;
        float* cout = out + (size_t)Hd * Bsz + (size_t)u * Bsz;
#pragma unroll
        for (int ni = 0; ni < 4; ++ni) {
            const int n = bn * 128 + wn * 64 + ni * 16 + fr;
            f32x4 a = acc[mi][ni];
            float co = crow[n], ho = hrow[n];
            float fg = sigm(a[0] + b0);
            float ig = sigm(a[1] + b1);
            float og = sigm(a[2] + b2);
            float gg = tanhf(a[3] + b3);
            float i_g = ig * gg;
            float nz = 1.0f - zc[ni], nzb = 1.0f - zbv[ni];
            float cn = zc[ni] * i_g + nz * nzb * co + nz * zbv[ni] * (fg * co + i_g);
            float tc2 = tanhf(cn);
            float hn = zc[ni] * og * tc2 + nz * nzb * ho + nz * zbv[ni] * og * tc2;
            hout[n] = hn; cout[n] = cn;
        }
    }

    // z-row finalize (32 blocks with bm==0 cover all 4096 columns)
    if (bm == 0 && t < 128) {
        float* outz = out + (size_t)2 * Hd * Bsz;
        int n = bn * 128 + t;
        float s = outz[n] + bias[4096];
        float zh = (s + 1.0f) * 0.5f;
        zh = fminf(fmaxf(zh, 0.0f), 1.0f);
        outz[n] = (zh > 0.5f) ? 1.0f : 0.0f;
    }
}

extern "C" void kernel_launch(void* const* d_in, const int* in_sizes, int n_in,
                              void* d_out, int out_size, void* d_ws, size_t ws_size,
                              hipStream_t stream) {
    (void)in_sizes; (void)n_in; (void)out_size; (void)ws_size;
    const float* c    = (const float*)d_in[0];
    const float* hb   = (const float*)d_in[1];
    const float* h    = (const float*)d_in[2];
    const float* ht   = (const float*)d_in[3];
    const float* z    = (const float*)d_in[4];
    const float* zb   = (const float*)d_in[5];
    const float* U11  = (const float*)d_in[6];
    const float* U21  = (const float*)d_in[7];
    const float* W01  = (const float*)d_in[8];
    const float* bias = (const float*)d_in[9];
    float* out = (float*)d_out;

    u16* Ab = (u16*)d_ws;                          // 256*96*512*2B = 25.2 MB
    u16* Bb = Ab + (size_t)256 * NTt * CH;         // 25.2 MB

    hipFuncSetAttribute(reinterpret_cast<const void*>(gemm_fused),
                        hipFuncAttributeMaxDynamicSharedMemorySize, 49152);

    prep_A<<<dim3(256, 6), 256, 0, stream>>>(U11, U21, W01, Ab, out);
    prep_B<<<dim3(128, 48), 256, 0, stream>>>(hb, ht, h, z, zb, U11, U21, W01, Bb, out);
    gemm_fused<<<512, 256, 49152, stream>>>(Ab, Bb, c, h, z, zb, bias, out);
}